// Round 4
// baseline (864.550 us; speedup 1.0000x reference)
//
#include <hip/hip_runtime.h>
#include <hip/hip_fp16.h>
#include <stdint.h>
#include <stddef.h>

// LSTM B=512,T=128,D=256,H=256,C=128, gates (i,j,f,o), FORGET_BIAS=1.
// R4: fused producer-consumer kernel.
//   shuffle_w  : Wk -> bf16 B-frags (Wx) + fp8 B-frags (Wh) in ws
//   lstm_fused : blocks 0..223 produce Zx (x@Wx+bias) chunk-by-chunk with
//                release-flags; blocks 224..255 run the recurrence, acquiring
//                chunks just-in-time. Rec loop: fp8 Wh in AGPRs, double-buffered
//                fp8 Ht in LDS (1 barrier/step), z prefetched 1 step ahead.

typedef __attribute__((ext_vector_type(8))) __bf16 bf16x8;
typedef __attribute__((ext_vector_type(4))) __bf16 bf16x4;
typedef __attribute__((ext_vector_type(4))) float  f32x4;

#define LDH   264     // bf16 row stride (xproj A-tile, HtB)
#define LDH8  264     // fp8 Ht row stride in bytes
#define NPROD 224
#define MAGIC 0x13579B

__device__ __forceinline__ f32x4 mfma_bf16(bf16x8 a, bf16x8 b, f32x4 c) {
    return __builtin_amdgcn_mfma_f32_16x16x32_bf16(a, b, c, 0, 0, 0);
}
__device__ __forceinline__ f32x4 mfma_fp8(long a, long b, f32x4 c) {
    return __builtin_amdgcn_mfma_f32_16x16x32_fp8_fp8(a, b, c, 0, 0, 0);
}
__device__ __forceinline__ float clamp30(float x) { return fminf(fmaxf(x, -30.f), 30.f); }
#define EXP2(x) __builtin_amdgcn_exp2f(x)
#define RCP(x)  __builtin_amdgcn_rcpf(x)
#define L2E  1.442695040f
#define L2E2 2.885390082f

// ---------------- 1) weight shuffle ----------------
__global__ __launch_bounds__(256) void shuffle_w(const float* __restrict__ Wk,
                                                 __bf16* __restrict__ WxF,
                                                 unsigned char* __restrict__ WhF) {
    int id = blockIdx.x * 256 + threadIdx.x;
    int part = id >> 15;                              // 0 = Wx (bf16), 1 = Wh (fp8)
    int i = id & 32767;
    int lane = i & 63, kt = (i >> 6) & 7, nt = i >> 9;
    int quad = lane >> 4, l16 = lane & 15;
    const float* src = Wk + (size_t)(part * 256 + kt * 32 + quad * 8) * 1024 + nt * 16 + l16;
    float w[8];
#pragma unroll
    for (int j = 0; j < 8; ++j) w[j] = src[(size_t)j * 1024];
    if (part == 0) {
        __bf16* dst = WxF + ((size_t)(nt * 8 + kt) * 64 + lane) * 8;
#pragma unroll
        for (int j = 0; j < 8; ++j) dst[j] = (__bf16)w[j];
    } else {
        int a = __builtin_amdgcn_cvt_pk_fp8_f32(w[0], w[1], 0, false);
        a     = __builtin_amdgcn_cvt_pk_fp8_f32(w[2], w[3], a, true);
        int b = __builtin_amdgcn_cvt_pk_fp8_f32(w[4], w[5], 0, false);
        b     = __builtin_amdgcn_cvt_pk_fp8_f32(w[6], w[7], b, true);
        int2 v = {a, b};
        *(int2*)(WhF + ((size_t)(nt * 8 + kt) * 64 + lane) * 8) = v;
    }
}

// ---------------- producer unit: z_x for (rb, 4 t's) ----------------
__device__ __forceinline__ void produce_unit(int rb, int tg, int tid,
        const float* __restrict__ x, const __bf16* __restrict__ WxF,
        const float* __restrict__ bias, __half* __restrict__ Zx, char* smem) {
    __bf16* At = (__bf16*)smem;
    const int wv = tid >> 6, lane = tid & 63, l16 = lane & 15, quad = lane >> 4;
#pragma unroll
    for (int rr = 0; rr < 8; ++rr) {
        int Arow = wv * 8 + rr;
        int tt = Arow >> 4, r = Arow & 15;
        const float4 xv = *((const float4*)(x + ((size_t)(rb * 16 + r) * 128 + tg * 4 + tt) * 256) + lane);
        bf16x4 xb = { (__bf16)xv.x, (__bf16)xv.y, (__bf16)xv.z, (__bf16)xv.w };
        *(bf16x4*)&At[Arow * LDH + lane * 4] = xb;
    }
    __syncthreads();

    f32x4 acc[4][8];
#pragma unroll
    for (int tt = 0; tt < 4; ++tt)
#pragma unroll
        for (int nt = 0; nt < 8; ++nt) acc[tt][nt] = (f32x4){0.f, 0.f, 0.f, 0.f};

#pragma unroll
    for (int kt = 0; kt < 8; ++kt) {
        bf16x8 af[4];
#pragma unroll
        for (int tt = 0; tt < 4; ++tt)
            af[tt] = *(const bf16x8*)&At[(tt * 16 + l16) * LDH + kt * 32 + quad * 8];
#pragma unroll
        for (int nt = 0; nt < 8; ++nt) {
            bf16x8 wf = *(const bf16x8*)&WxF[(((size_t)(wv * 8 + nt) * 8 + kt) * 64 + lane) * 8];
#pragma unroll
            for (int tt = 0; tt < 4; ++tt) acc[tt][nt] = mfma_bf16(af[tt], wf, acc[tt][nt]);
        }
    }

    float bb[8];
#pragma unroll
    for (int nt = 0; nt < 8; ++nt) {
        int col = wv * 128 + nt * 16 + l16;
        bb[nt] = bias[col] + ((col >= 512 && col < 768) ? 1.0f : 0.0f);
    }

    uint2* Lz2 = (uint2*)smem;
    const uint4* Ls = (const uint4*)smem;
#pragma unroll 1
    for (int tt = 0; tt < 4; ++tt) {
        __syncthreads();
#pragma unroll
        for (int nt = 0; nt < 8; ++nt) {
            union { __half h[4]; uint2 u; } pk;
#pragma unroll
            for (int r = 0; r < 4; ++r) pk.h[r] = __float2half(acc[tt][nt][r] + bb[nt]);
            Lz2[(((wv >> 1) * 8 + nt) * 64 + lane) * 2 + (wv & 1)] = pk.u;
        }
        __syncthreads();
        int t = tg * 4 + tt;
        uint4* dst = (uint4*)Zx + (size_t)(rb * 128 + t) * 2048;
#pragma unroll
        for (int k = 0; k < 4; ++k) {
            int e = k * 512 + tid;
            int wp = e & 3, ln = (e >> 2) & 63, nt2 = (e >> 8) & 7;
            dst[e] = Ls[(wp * 8 + nt2) * 64 + ln];
        }
    }
}

// slow scalar fallback (fp32, exact) — only if flag times out (non-coresidency)
__device__ __attribute__((noinline)) void fallback_chunk(int rb, int tg, int tid,
        const float* __restrict__ x, const float* __restrict__ Wk,
        const float* __restrict__ bias, __half* __restrict__ Zx) {
    for (int i = 0; i < 128; ++i) {
        int v = tid + 512 * i;
        int idx = v & 31, ln = (v >> 5) & 63, cw = (v >> 11) & 7, tt = v >> 14;
        int r = idx & 3, ghf = idx >> 2;
        int g = ghf >> 1, hf = ghf & 1;
        int col = g * 256 + hf * 128 + cw * 16 + (ln & 15);
        int row = (ln >> 4) * 4 + r;
        int t = tg * 4 + tt;
        const float* xr = x + ((size_t)(rb * 16 + row) * 128 + t) * 256;
        float s = bias[col] + ((g == 2) ? 1.0f : 0.0f);
        for (int k = 0; k < 256; ++k) s += xr[k] * Wk[(size_t)k * 1024 + col];
        Zx[(size_t)(rb * 128 + t) * 16384 + (size_t)(cw * 64 + ln) * 32 + idx] = __float2half(s);
    }
}

// ---------------- fused kernel ----------------
__global__ __launch_bounds__(512, 2) void lstm_fused(
        const float* __restrict__ x, const float* __restrict__ Wk,
        const __bf16* __restrict__ WxF, const long* __restrict__ WhF,
        const float* __restrict__ bias, __half* __restrict__ Zx,
        int* __restrict__ flag,
        const float* __restrict__ wout, const float* __restrict__ bout,
        float* __restrict__ out) {
    __shared__ __attribute__((aligned(16))) char psm[64 * LDH * 2];
    __shared__ __attribute__((aligned(16))) unsigned char Ht[2][16 * LDH8];
    __shared__ __attribute__((aligned(16))) __bf16 HtB[16 * LDH];
    __shared__ int s_to;
    const int tid = threadIdx.x;
    const int bid = blockIdx.x;

    if (bid < NPROD) {
        // ---------------- producer ----------------
        for (int u = bid; u < 1024; u += NPROD) {
            int tg = u >> 5, rb = u & 31;
            produce_unit(rb, tg, tid, x, WxF, bias, Zx, psm);
            __threadfence();
            __syncthreads();
            if (tid == 0)
                __hip_atomic_store(&flag[u], MAGIC, __ATOMIC_RELEASE, __HIP_MEMORY_SCOPE_AGENT);
            __syncthreads();
        }
        return;
    }

    // ---------------- consumer (recurrence) ----------------
    const int rb = bid - NPROD;
    const int wv = tid >> 6, lane = tid & 63, l16 = lane & 15, quad = lane >> 4;

    long wreg[64];
#pragma unroll
    for (int n = 0; n < 8; ++n) {
        int ng = (n >> 1) * 16 + (n & 1) * 8 + wv;
#pragma unroll
        for (int kt = 0; kt < 8; ++kt)
            wreg[kt * 8 + n] = WhF[(size_t)(ng * 8 + kt) * 64 + lane];
    }
    for (int i = tid; i < 16 * LDH8; i += 512) Ht[0][i] = 0;
    float c_[2][4] = {{0.f,0.f,0.f,0.f},{0.f,0.f,0.f,0.f}};
    float hr[2][4] = {{0.f,0.f,0.f,0.f},{0.f,0.f,0.f,0.f}};
    __syncthreads();

    auto wait_chunk = [&](int tc) {
        if (tid == 0) {
            int ok = 0;
            for (int s = 0; s < 20000; ++s) {
                if (__hip_atomic_load(&flag[tc * 32 + rb], __ATOMIC_ACQUIRE,
                                      __HIP_MEMORY_SCOPE_AGENT) == MAGIC) { ok = 1; break; }
                __builtin_amdgcn_s_sleep(4);
            }
            s_to = !ok;
        }
        __syncthreads();
        if (s_to) { fallback_chunk(rb, tc, tid, x, Wk, bias, Zx); __syncthreads(); }
    };

    const __half* zbase = Zx + (((size_t)rb * 1024 + wv) * 64 + lane) * 32;
    union Zreg { uint4 q[4]; unsigned u[16]; };
    Zreg zc, zn;

    wait_chunk(0);
    {
        const uint4* zp = (const uint4*)zbase;
        zc.q[0] = zp[0]; zc.q[1] = zp[1]; zc.q[2] = zp[2]; zc.q[3] = zp[3];
    }

#pragma unroll 1
    for (int t = 0; t < 128; ++t) {
        long af[8];
#pragma unroll
        for (int kt = 0; kt < 8; ++kt)
            af[kt] = *(const long*)&Ht[t & 1][l16 * LDH8 + kt * 32 + quad * 8];

        if (t < 127) {                       // prefetch z(t+1); arrives during MFMA
            if (((t + 1) & 3) == 0) wait_chunk((t + 1) >> 2);
            const uint4* zp = (const uint4*)(zbase + (size_t)(t + 1) * 16384);
            zn.q[0] = zp[0]; zn.q[1] = zp[1]; zn.q[2] = zp[2]; zn.q[3] = zp[3];
        }

        f32x4 acc[8];
#pragma unroll
        for (int n = 0; n < 8; ++n) acc[n] = (f32x4){0.f, 0.f, 0.f, 0.f};
#pragma unroll
        for (int kt = 0; kt < 8; ++kt)
#pragma unroll
            for (int n = 0; n < 8; ++n)
                acc[n] = mfma_fp8(af[kt], wreg[kt * 8 + n], acc[n]);

        // epilogue -> write OTHER Ht buffer (no WAR with this step's reads)
#pragma unroll
        for (int hf = 0; hf < 2; ++hf) {
#pragma unroll
            for (int r = 0; r < 4; ++r) {
#define ZGET(ix) __half2float(((ix) & 1) ? ((__half2*)&zc.u[(ix) >> 1])->y : ((__half2*)&zc.u[(ix) >> 1])->x)
                float iv = acc[0 + hf][r] + ZGET((0 * 2 + hf) * 4 + r);
                float jv = acc[2 + hf][r] + ZGET((1 * 2 + hf) * 4 + r);
                float fv = acc[4 + hf][r] + ZGET((2 * 2 + hf) * 4 + r);
                float ov = acc[6 + hf][r] + ZGET((3 * 2 + hf) * 4 + r);
#undef ZGET
                float Ei = EXP2(clamp30(-L2E  * iv));
                float Ef = EXP2(clamp30(-L2E  * fv));
                float G  = EXP2(clamp30(-L2E2 * jv));
                float pI = 1.f + Ei, pF = 1.f + Ef, pG = 1.f + G, mG = 1.f - G;
                float t1 = pI * pG;
                float cn = (c_[hf][r] * t1 + pF * mG) * RCP(pF * t1);
                c_[hf][r] = cn;
                float Ec = EXP2(clamp30(-L2E2 * cn));
                float Eo = EXP2(clamp30(-L2E  * ov));
                float h  = (1.f - Ec) * RCP((1.f + Ec) * (1.f + Eo));
                hr[hf][r] = h;
                unsigned pb = (unsigned)__builtin_amdgcn_cvt_pk_fp8_f32(h, h, 0, false);
                Ht[(t + 1) & 1][(quad * 4 + r) * LDH8 + hf * 128 + wv * 16 + l16] = (unsigned char)pb;
            }
        }
        if (t < 127) { zc.q[0] = zn.q[0]; zc.q[1] = zn.q[1]; zc.q[2] = zn.q[2]; zc.q[3] = zn.q[3]; }
        __syncthreads();   // publishes Ht(t+1); drains the zn prefetch (already arrived)
    }

    // ---- output projection in bf16 ----
#pragma unroll
    for (int hf = 0; hf < 2; ++hf)
#pragma unroll
        for (int r = 0; r < 4; ++r)
            HtB[(quad * 4 + r) * LDH + hf * 128 + wv * 16 + l16] = (__bf16)hr[hf][r];
    __syncthreads();

    bf16x8 wo[8];
#pragma unroll
    for (int kt = 0; kt < 8; ++kt) {
        bf16x8 f;
#pragma unroll
        for (int j = 0; j < 8; ++j)
            f[j] = (__bf16)wout[(size_t)(kt * 32 + quad * 8 + j) * 128 + wv * 16 + l16];
        wo[kt] = f;
    }
    f32x4 oa = {0.f, 0.f, 0.f, 0.f};
#pragma unroll
    for (int kt = 0; kt < 8; ++kt) {
        bf16x8 af = *(const bf16x8*)&HtB[l16 * LDH + kt * 32 + quad * 8];
        oa = mfma_bf16(af, wo[kt], oa);
    }
    float bo = bout[wv * 16 + l16];
#pragma unroll
    for (int r = 0; r < 4; ++r)
        out[(size_t)(rb * 16 + quad * 4 + r) * 128 + wv * 16 + l16] = oa[r] + bo;
}

extern "C" void kernel_launch(void* const* d_in, const int* in_sizes, int n_in,
                              void* d_out, int out_size, void* d_ws, size_t ws_size,
                              hipStream_t stream) {
    const float* x    = (const float*)d_in[0];
    const float* Wk   = (const float*)d_in[1];
    const float* bias = (const float*)d_in[2];
    const float* wout = (const float*)d_in[3];
    const float* bout = (const float*)d_in[4];
    float* out = (float*)d_out;

    __bf16*        WxF  = (__bf16*)d_ws;                      // 512 KB
    unsigned char* WhF  = (unsigned char*)d_ws + 524288;      // 256 KB (fp8)
    int*           flag = (int*)((char*)d_ws + 786432);       // 4 KB (1024 flags)
    __half*        Zx   = (__half*)((char*)d_ws + 1048576);   // 128 MB

    shuffle_w<<<256, 256, 0, stream>>>(Wk, WxF, WhF);
    lstm_fused<<<256, 512, 0, stream>>>(x, Wk, WxF, (const long*)WhF,
                                        bias, Zx, flag, wout, bout, out);
}

// Round 5
// 523.886 us; speedup vs baseline: 1.6503x; 1.6503x over previous
//
#include <hip/hip_runtime.h>
#include <hip/hip_fp16.h>
#include <stdint.h>
#include <stddef.h>

// LSTM B=512,T=128,D=256,H=256,C=128, gates (i,j,f,o), FORGET_BIAS=1.
// R5: back to sequential 3-kernel structure (R4's producer/consumer regressed).
//  1) shuffle_w : Wk -> bf16 B-frags (Wx) + fp8-e4m3 B-frags (Wh)
//  2) xproj     : Zx = x@Wx + bias(+1 on f), PLANE-SEPARATED layout:
//                 Zx[plane=src wave 0..7][rb][t][nt][lane]{4 fp16} -> both the
//                 producer stores AND consumer loads are fully coalesced; no
//                 LDS transpose, no epilogue barriers.
//  3) lstm_rec  : 32 blocks x 512 thr. Wh fp8 in AGPRs (128), double-buffered
//                 fp8 Ht in A-FRAGMENT order (perfect LDS banking), ONE barrier
//                 per step, z(t+1) prefetched a full step ahead (latency hidden).

typedef __attribute__((ext_vector_type(8))) __bf16 bf16x8;
typedef __attribute__((ext_vector_type(4))) __bf16 bf16x4;
typedef __attribute__((ext_vector_type(4))) float  f32x4;

#define LDH   264          // bf16 row stride (xproj A-tile, HtB): perfect b128 banking
#define ZPS   2097152ull   // Zx plane stride in uint2 (32*128*8*64)

__device__ __forceinline__ f32x4 mfma_bf16(bf16x8 a, bf16x8 b, f32x4 c) {
    return __builtin_amdgcn_mfma_f32_16x16x32_bf16(a, b, c, 0, 0, 0);
}
__device__ __forceinline__ f32x4 mfma_fp8(long a, long b, f32x4 c) {
    return __builtin_amdgcn_mfma_f32_16x16x32_fp8_fp8(a, b, c, 0, 0, 0);
}
__device__ __forceinline__ float clamp30(float x) { return fminf(fmaxf(x, -30.f), 30.f); }
#define EXP2(x) __builtin_amdgcn_exp2f(x)
#define RCP(x)  __builtin_amdgcn_rcpf(x)
#define L2E  1.442695040f
#define L2E2 2.885390082f

// ---------------- 1) weight shuffle ----------------
__global__ __launch_bounds__(256) void shuffle_w(const float* __restrict__ Wk,
                                                 __bf16* __restrict__ WxF,
                                                 unsigned char* __restrict__ WhF) {
    int id = blockIdx.x * 256 + threadIdx.x;
    int part = id >> 15;                              // 0 = Wx (bf16), 1 = Wh (fp8)
    int i = id & 32767;
    int lane = i & 63, kt = (i >> 6) & 7, nt = i >> 9;
    int quad = lane >> 4, l16 = lane & 15;
    const float* src = Wk + (size_t)(part * 256 + kt * 32 + quad * 8) * 1024 + nt * 16 + l16;
    float w[8];
#pragma unroll
    for (int j = 0; j < 8; ++j) w[j] = src[(size_t)j * 1024];
    if (part == 0) {
        __bf16* dst = WxF + ((size_t)(nt * 8 + kt) * 64 + lane) * 8;
#pragma unroll
        for (int j = 0; j < 8; ++j) dst[j] = (__bf16)w[j];
    } else {
        int a = __builtin_amdgcn_cvt_pk_fp8_f32(w[0], w[1], 0, false);
        a     = __builtin_amdgcn_cvt_pk_fp8_f32(w[2], w[3], a, true);
        int b = __builtin_amdgcn_cvt_pk_fp8_f32(w[4], w[5], 0, false);
        b     = __builtin_amdgcn_cvt_pk_fp8_f32(w[6], w[7], b, true);
        int2 v = {a, b};
        *(int2*)(WhF + ((size_t)(nt * 8 + kt) * 64 + lane) * 8) = v;
    }
}

// ---------------- 2) x-projection (plane-separated Zx) ----------------
__global__ __launch_bounds__(512, 2) void xproj(const float* __restrict__ x,
        const __bf16* __restrict__ WxF, const float* __restrict__ bias,
        uint2* __restrict__ Zx) {
    __shared__ __attribute__((aligned(16))) __bf16 At[64 * LDH];
    const int tid = threadIdx.x, wv = tid >> 6, lane = tid & 63;
    const int l16 = lane & 15, quad = lane >> 4;
    const int rb = blockIdx.x & 31, tg = blockIdx.x >> 5;

    // stage A: 64 rows = 16 b-rows x 4 t (coalesced float4); perfect LDS banking
#pragma unroll
    for (int rr = 0; rr < 8; ++rr) {
        int Arow = wv * 8 + rr;
        int tt = Arow >> 4, r = Arow & 15;
        const float4 xv = *((const float4*)(x + ((size_t)(rb * 16 + r) * 128 + tg * 4 + tt) * 256) + lane);
        bf16x4 xb = { (__bf16)xv.x, (__bf16)xv.y, (__bf16)xv.z, (__bf16)xv.w };
        *(bf16x4*)&At[Arow * LDH + lane * 4] = xb;
    }
    __syncthreads();

    f32x4 acc[4][8];
#pragma unroll
    for (int tt = 0; tt < 4; ++tt)
#pragma unroll
        for (int nt = 0; nt < 8; ++nt) acc[tt][nt] = (f32x4){0.f, 0.f, 0.f, 0.f};

#pragma unroll
    for (int kt = 0; kt < 8; ++kt) {
        bf16x8 af[4];
#pragma unroll
        for (int tt = 0; tt < 4; ++tt)
            af[tt] = *(const bf16x8*)&At[(tt * 16 + l16) * LDH + kt * 32 + quad * 8];
#pragma unroll
        for (int nt = 0; nt < 8; ++nt) {
            bf16x8 wf = *(const bf16x8*)&WxF[(((size_t)(wv * 8 + nt) * 8 + kt) * 64 + lane) * 8];
#pragma unroll
            for (int tt = 0; tt < 4; ++tt) acc[tt][nt] = mfma_bf16(af[tt], wf, acc[tt][nt]);
        }
    }

    // epilogue: +bias (+forget), direct coalesced uint2 stores into plane wv.
    // Zx elem (plane=wv)[rb][t][nt][lane] = {z(r=0..3)} for col wv*128+nt*16+l16,
    // row quad*4+r  (consumer lane == producer lane: quad*16+l16).
#pragma unroll
    for (int nt = 0; nt < 8; ++nt) {
        int col = wv * 128 + nt * 16 + l16;
        float bb = bias[col] + ((col >= 512 && col < 768) ? 1.0f : 0.0f);
#pragma unroll
        for (int tt = 0; tt < 4; ++tt) {
            int t = tg * 4 + tt;
            union { __half h[4]; uint2 u; } pk;
#pragma unroll
            for (int r = 0; r < 4; ++r) pk.h[r] = __float2half(acc[tt][nt][r] + bb);
            Zx[(size_t)wv * ZPS + ((size_t)(rb * 128 + t) * 8 + nt) * 64 + lane] = pk.u;
        }
    }
}

// ---------------- 3) recurrent loop ----------------
__global__ __launch_bounds__(512, 2) void lstm_rec(const long* __restrict__ WhF,
        const uint2* __restrict__ Zx, const float* __restrict__ wout,
        const float* __restrict__ bout, float* __restrict__ out) {
    // Ht in A-FRAGMENT order: HtF[buf][kt*512 + lane*8 + j] (fp8).
    // b64 reads at lane*8 -> each bank touched exactly 4x (perfect).
    __shared__ __attribute__((aligned(16))) unsigned char HtF[2][4096];
    __shared__ __attribute__((aligned(16))) __bf16 HtB[16 * LDH];
    const int tid = threadIdx.x, wv = tid >> 6, lane = tid & 63;
    const int l16 = lane & 15, quad = lane >> 4;
    const int rb = blockIdx.x;

    // Wh fp8 B-frags, register(AGPR)-resident: 64 x 8B = 128 regs
    long wreg[64];
#pragma unroll
    for (int n = 0; n < 8; ++n) {
        int ng = (n >> 1) * 16 + (n & 1) * 8 + wv;   // cols g*256+hf*128+wv*16+l16
#pragma unroll
        for (int kt = 0; kt < 8; ++kt)
            wreg[kt * 8 + n] = WhF[(size_t)(ng * 8 + kt) * 64 + lane];
    }
    if (tid < 512) ((long*)HtF[0])[tid] = 0;   // h(0) = 0
    float c_[2][4] = {{0.f,0.f,0.f,0.f},{0.f,0.f,0.f,0.f}};
    float hr[2][4] = {{0.f,0.f,0.f,0.f},{0.f,0.f,0.f,0.f}};

    // epilogue scatter base into HtF (A-frag position of col hf*128+wv*16+l16,
    // row quad*4+r):  kt_d = hf*4 + (wv>>1), quad_d = (2*wv + (l16>>3)) & 3,
    // lane_d = quad_d*16 + quad*4 + r, byte j = l16 & 7.
    const int quad_d = (2 * wv + (l16 >> 3)) & 3;
    const int wbase = (wv >> 1) * 512 + (quad_d * 16 + quad * 4) * 8 + (l16 & 7);

    const size_t zidx0 = ((size_t)rb * 128 * 8 + wv) * 64 + lane;
    uint2 zc[8], zn[8];
#pragma unroll
    for (int p = 0; p < 8; ++p) zc[p] = Zx[p * ZPS + zidx0];
    __syncthreads();

#pragma unroll 1
    for (int t = 0; t < 128; ++t) {
        // prefetch z(t+1): 8 coalesced 8B loads; consumed NEXT iteration,
        // so the end-of-step barrier's vmcnt drain finds them arrived.
        if (t < 127) {
            size_t zi = zidx0 + (size_t)(t + 1) * 512;
#pragma unroll
            for (int p = 0; p < 8; ++p) zn[p] = Zx[p * ZPS + zi];
        }

        long af[8];
#pragma unroll
        for (int kt = 0; kt < 8; ++kt)
            af[kt] = *(const long*)&HtF[t & 1][kt * 512 + lane * 8];

        f32x4 acc[8];
#pragma unroll
        for (int n = 0; n < 8; ++n) acc[n] = (f32x4){0.f, 0.f, 0.f, 0.f};
#pragma unroll
        for (int kt = 0; kt < 8; ++kt)
#pragma unroll
            for (int n = 0; n < 8; ++n)
                acc[n] = mfma_fp8(af[kt], wreg[kt * 8 + n], acc[n]);

        // gate epilogue (5 exp2 + 2 rcp per h); writes go to the OTHER buffer
        unsigned char* Hw = &HtF[(t + 1) & 1][wbase];
#pragma unroll
        for (int hf = 0; hf < 2; ++hf) {
#pragma unroll
            for (int r = 0; r < 4; ++r) {
#define ZGET(p, r_) __half2float(((const __half*)&zc[p])[r_])
                float iv = acc[0 + hf][r] + ZGET(0 + hf, r);
                float jv = acc[2 + hf][r] + ZGET(2 + hf, r);
                float fv = acc[4 + hf][r] + ZGET(4 + hf, r);
                float ov = acc[6 + hf][r] + ZGET(6 + hf, r);
#undef ZGET
                float Ei = EXP2(clamp30(-L2E  * iv));
                float Ef = EXP2(clamp30(-L2E  * fv));
                float G  = EXP2(clamp30(-L2E2 * jv));
                float pI = 1.f + Ei, pF = 1.f + Ef, pG = 1.f + G, mG = 1.f - G;
                float t1 = pI * pG;
                float cn = (c_[hf][r] * t1 + pF * mG) * RCP(pF * t1);
                c_[hf][r] = cn;
                float Ec = EXP2(clamp30(-L2E2 * cn));
                float Eo = EXP2(clamp30(-L2E  * ov));
                float h  = (1.f - Ec) * RCP((1.f + Ec) * (1.f + Eo));
                hr[hf][r] = h;
                unsigned pb = (unsigned)__builtin_amdgcn_cvt_pk_fp8_f32(h, h, 0, false);
                Hw[hf * 2048 + r * 8] = (unsigned char)pb;
            }
        }
#pragma unroll
        for (int p = 0; p < 8; ++p) zc[p] = zn[p];
        __syncthreads();   // publish HtF[(t+1)&1]; zn already arrived
    }

    // ---- output projection in bf16 ----
#pragma unroll
    for (int hf = 0; hf < 2; ++hf)
#pragma unroll
        for (int r = 0; r < 4; ++r)
            HtB[(quad * 4 + r) * LDH + hf * 128 + wv * 16 + l16] = (__bf16)hr[hf][r];
    __syncthreads();

    bf16x8 wo[8];
#pragma unroll
    for (int kt = 0; kt < 8; ++kt) {
        bf16x8 f;
#pragma unroll
        for (int j = 0; j < 8; ++j)
            f[j] = (__bf16)wout[(size_t)(kt * 32 + quad * 8 + j) * 128 + wv * 16 + l16];
        wo[kt] = f;
    }
    f32x4 oa = {0.f, 0.f, 0.f, 0.f};
#pragma unroll
    for (int kt = 0; kt < 8; ++kt) {
        bf16x8 af = *(const bf16x8*)&HtB[l16 * LDH + kt * 32 + quad * 8];
        oa = mfma_bf16(af, wo[kt], oa);
    }
    float bo = bout[wv * 16 + l16];
#pragma unroll
    for (int r = 0; r < 4; ++r)
        out[(size_t)(rb * 16 + quad * 4 + r) * 128 + wv * 16 + l16] = oa[r] + bo;
}

extern "C" void kernel_launch(void* const* d_in, const int* in_sizes, int n_in,
                              void* d_out, int out_size, void* d_ws, size_t ws_size,
                              hipStream_t stream) {
    const float* x    = (const float*)d_in[0];
    const float* Wk   = (const float*)d_in[1];
    const float* bias = (const float*)d_in[2];
    const float* wout = (const float*)d_in[3];
    const float* bout = (const float*)d_in[4];
    float* out = (float*)d_out;

    __bf16*        WxF = (__bf16*)d_ws;                      // 512 KB
    unsigned char* WhF = (unsigned char*)d_ws + 524288;      // 256 KB (fp8)
    uint2*         Zx  = (uint2*)((char*)d_ws + 1048576);    // 128 MB, 8 planes

    shuffle_w<<<256, 256, 0, stream>>>(Wk, WxF, WhF);
    xproj<<<1024, 512, 0, stream>>>(x, WxF, bias, Zx);
    lstm_rec<<<32, 512, 0, stream>>>((const long*)WhF, Zx, wout, bout, out);
}